// Round 5
// baseline (167.478 us; speedup 1.0000x reference)
//
#include <hip/hip_runtime.h>
#include <hip/hip_bf16.h>

// DCNv2: B=4, C=64, H=W=128, O=64, KS=3, N=9, PAD=1. I/O float32.
#define BB 4
#define CC 64
#define HH 128
#define WW 128
#define OO 64
#define NN 9
#define HW 16384
#define HP 130
#define WP 130

// ---- ws layout (float-slot offsets) ----
// 0        wpmb bf16 [32][576]   (rows 0..17 w_p, 18..26 w_m, 27..31 zero)
// 9216     bias fp32 (18 b_p then 9 b_m)
// 9248     wcb  bf16 [o(64)][K(576)], K = kt*64+c
// 27680    xt   bf16 [b][hw][c]
#define WPMB_F  0
#define BPM_OFF 9216
#define WCB_F   9248
#define XT_F    27680

typedef __attribute__((ext_vector_type(8))) short s8v;
typedef __attribute__((ext_vector_type(8))) unsigned short u8v;
typedef __attribute__((ext_vector_type(4))) unsigned short u4v;
typedef __attribute__((ext_vector_type(4))) float f4v;

__device__ __forceinline__ unsigned short f2bu(float f) {   // fp32 -> bf16 bits (RNE)
    unsigned int b = __float_as_uint(f);
    return (unsigned short)((b + 0x7FFFu + ((b >> 16) & 1u)) >> 16);
}

#define MF(a, bb, c) __builtin_amdgcn_mfma_f32_16x16x32_bf16(a, bb, c, 0, 0, 0)
#define FOLD(g, d, o) { o[0] = fmaf(g, d[0], o[0]); o[1] = fmaf(g, d[1], o[1]); \
                        o[2] = fmaf(g, d[2], o[2]); o[3] = fmaf(g, d[3], o[3]); }

// blocks [0,1024): NCHW fp32 -> NHWC bf16 transpose via LDS tile, 16B loads + 16B stores.
// blocks [1024,1248): weight prep.
__global__ void __launch_bounds__(256) k_pxt(const float* __restrict__ x,
                                             const float* __restrict__ wp,
                                             const float* __restrict__ bp,
                                             const float* __restrict__ wm,
                                             const float* __restrict__ bm,
                                             const float* __restrict__ wcv,
                                             float* __restrict__ ws) {
    int blk = blockIdx.x;
    int t = threadIdx.x;
    if (blk >= 1024) {                       // ---- weight prep path ----
        int tid = (blk - 1024) * 256 + t;
        if (tid < 18432) {                   // wpmb [32][576]
            int r = tid / 576;
            int kk = tid % 576;              // kk = kt*64 + c
            int kt = kk >> 6;
            int c = kk & 63;
            int dy = kt / 3, dx = kt % 3;
            float v = 0.f;
            if (r < 18)       v = wp[((r * 64 + c) * 3 + dy) * 3 + dx];
            else if (r < 27)  v = wm[(((r - 18) * 64 + c) * 3 + dy) * 3 + dx];
            ((unsigned short*)(ws + WPMB_F))[tid] = f2bu(v);
        } else if (tid < 18459) {
            int i = tid - 18432;
            ws[BPM_OFF + i] = (i < 18) ? bp[i] : bm[i - 18];
        } else if (tid >= 20480) {           // wcb [64][576], tid < 57344 by grid
            int d = tid - 20480;
            int o = d / 576;
            int kk = d % 576;
            int kt = kk >> 6;
            int c = kk & 63;
            ((unsigned short*)(ws + WCB_F))[o * 576 + kk] = f2bu(wcv[(o * 64 + c) * 9 + kt]);
        }
        return;
    }
    // ---- transpose: block = 64 hw x 64 ch, tile stored [hw][c] ----
    __shared__ unsigned short tile[64][72];   // 16B-aligned rows (144B)
    int b = blk >> 8;
    int hw0 = (blk & 255) * 64;
    unsigned short* xt = (unsigned short*)(ws + XT_F);

#pragma unroll
    for (int p = 0; p < 4; p++) {            // coalesced float4 reads: 256B/instr per c-row
        int c = p * 16 + (t >> 4);
        int h4 = (t & 15) * 4;
        float4 v = *(const float4*)(x + ((size_t)(b * 64 + c)) * HW + hw0 + h4);
        tile[h4 + 0][c] = f2bu(v.x);
        tile[h4 + 1][c] = f2bu(v.y);
        tile[h4 + 2][c] = f2bu(v.z);
        tile[h4 + 3][c] = f2bu(v.w);
    }
    __syncthreads();
#pragma unroll
    for (int p = 0; p < 2; p++) {            // contiguous 16B/lane stores: 1KB/wave
        int hw = p * 32 + (t >> 3);
        int cb = (t & 7) * 8;
        u8v o = *(const u8v*)(&tile[hw][cb]);
        *(u8v*)(xt + ((size_t)(b * HW + hw0 + hw)) * 64 + cb) = o;
    }
}

// Fused offset-conv + sampler + einsum. Wave-synchronous, zero __syncthreads.
// NO blend: gathered bf16 rows ARE the MFMA B-fragments; bilinear weights g_c
// (modulation folded in) applied as f32 scalar fold of per-corner MFMA results.
// out[o,p] = sum_tap sum_corner g_c * (sum_ch w[o,ch] x[corner,ch])
__global__ void __launch_bounds__(256) k_main(const float* __restrict__ ws,
                                              float* __restrict__ out) {
    __shared__ float pxmL[4][3][NN][16];     // [wave][{px,py,m}][tap][pixel]

    int t = threadIdx.x;
    int lane = t & 63;
    int wv = t >> 6;
    int ln15 = lane & 15;
    int quad = lane >> 4;

    int braw = blockIdx.x;                   // 1024 = 8 XCD * 128: chunked swizzle
    int blk = ((braw & 7) << 7) | (braw >> 3);
    int b = blk >> 8;
    int hw0 = (blk & 255) * 64 + wv * 16;    // this wave's 16-pixel tile

    const unsigned short* wpmb = (const unsigned short*)(ws + WPMB_F);
    const unsigned short* wcb  = (const unsigned short*)(ws + WCB_F);
    const unsigned short* xtb  = (const unsigned short*)(ws + XT_F) + (size_t)b * HW * 64;
    const float* bpm = ws + BPM_OFF;

    int gp = hw0 + ln15;                     // this lane's pixel (B-frag column)
    int ph = gp >> 7, pw = gp & 127;
    int co = quad * 8;                       // channel offset within 32-wide k group

    const s8v zs = (s8v){0, 0, 0, 0, 0, 0, 0, 0};
    const f4v zf = (f4v){0.f, 0.f, 0.f, 0.f};

    // ================= PHASE 1: offset/modulation GEMM (M=27, K=576) =================
    {
        f4v p0 = zf, p1 = zf;
        s8v bC0, bC1, aC00, aC01, aC10, aC11;
        {   // prologue tap 0 (dy=0,dx=0)
            int h2 = ph - 1, w2 = pw - 1;
            bool val = ((unsigned)h2 < 128u) && ((unsigned)w2 < 128u);
            bC0 = zs; bC1 = zs;
            if (val) {
                const unsigned short* s = xtb + ((size_t)(h2 * 128 + w2)) * 64 + co;
                bC0 = *(const s8v*)(s);
                bC1 = *(const s8v*)(s + 32);
            }
            const unsigned short* a = wpmb + ln15 * 576 + co;
            aC00 = *(const s8v*)(a);
            aC01 = *(const s8v*)(a + 32);
            aC10 = *(const s8v*)(a + 16 * 576);
            aC11 = *(const s8v*)(a + 16 * 576 + 32);
        }
#pragma unroll 3
        for (int kt = 0; kt < 9; kt++) {
            s8v bN0 = zs, bN1 = zs, aN00 = zs, aN01 = zs, aN10 = zs, aN11 = zs;
            if (kt < 8) {
                int k2 = kt + 1;
                const unsigned short* a = wpmb + ln15 * 576 + k2 * 64 + co;
                aN00 = *(const s8v*)(a);
                aN01 = *(const s8v*)(a + 32);
                aN10 = *(const s8v*)(a + 16 * 576);
                aN11 = *(const s8v*)(a + 16 * 576 + 32);
                int dy = k2 / 3, dx = k2 - dy * 3;
                int h2 = ph + dy - 1, w2 = pw + dx - 1;
                bool val = ((unsigned)h2 < 128u) && ((unsigned)w2 < 128u);
                if (val) {
                    const unsigned short* s = xtb + ((size_t)(h2 * 128 + w2)) * 64 + co;
                    bN0 = *(const s8v*)(s);
                    bN1 = *(const s8v*)(s + 32);
                }
            }
            p0 = MF(aC00, bC0, p0);
            p1 = MF(aC10, bC0, p1);
            p0 = MF(aC01, bC1, p0);
            p1 = MF(aC11, bC1, p1);
            bC0 = bN0; bC1 = bN1;
            aC00 = aN00; aC01 = aN01; aC10 = aN10; aC11 = aN11;
        }
        // epilogue -> per-wave pxm LDS. pixel = ln15, oc = mt*16 + quad*4 + r
#pragma unroll
        for (int mt = 0; mt < 2; mt++) {
#pragma unroll
            for (int r = 0; r < 4; r++) {
                int oc = mt * 16 + quad * 4 + r;
                if (oc < 27) {
                    float v = (mt ? p1[r] : p0[r]) + bpm[oc];
                    if (oc < 9) {
                        pxmL[wv][0][oc][ln15] = v + (float)(oc / 3 - 1) + (float)(ph + 1);
                    } else if (oc < 18) {
                        int k = oc - 9;
                        pxmL[wv][1][k][ln15] = v + (float)(k % 3 - 1) + (float)(pw + 1);
                    } else {
                        int k = oc - 18;
                        pxmL[wv][2][k][ln15] = 1.f / (1.f + __expf(-v));
                    }
                }
            }
        }
    }
    __builtin_amdgcn_wave_barrier();

    // ================= PHASE 2: corner-GEMM + f32 fold (M=64, K=576) =================
    f4v o0 = zf, o1 = zf, o2 = zf, o3 = zf;

    auto desc = [&](int kt, float& g0, float& g1, float& g2, float& g3,
                    const unsigned short*& q0, const unsigned short*& q1,
                    const unsigned short*& q2, const unsigned short*& q3) {
        float px = pxmL[wv][0][kt][ln15];
        float py = pxmL[wv][1][kt][ln15];
        float mk = pxmL[wv][2][kt][ln15];
        float fx = floorf(px), fy = floorf(py);
        float pxc = fminf(fmaxf(px, 0.f), (float)(HP - 1));
        float pyc = fminf(fmaxf(py, 0.f), (float)(WP - 1));
        int qltx = (int)fminf(fmaxf(fx, 0.f), (float)(HP - 1));
        int qlty = (int)fminf(fmaxf(fy, 0.f), (float)(WP - 1));
        int qrbx = (int)fminf(fmaxf(fx + 1.f, 0.f), (float)(HP - 1));
        int qrby = (int)fminf(fmaxf(fy + 1.f, 0.f), (float)(WP - 1));

        float gltx = 1.f + ((float)qltx - pxc);
        float glty = 1.f + ((float)qlty - pyc);
        float grbx = 1.f - ((float)qrbx - pxc);
        float grby = 1.f - ((float)qrby - pyc);

        bool vlx = (qltx >= 1) && (qltx <= HH);
        bool vly = (qlty >= 1) && (qlty <= WW);
        bool vrx = (qrbx >= 1) && (qrbx <= HH);
        bool vry = (qrby >= 1) && (qrby <= WW);
        g0 = (vlx && vly) ? gltx * glty * mk : 0.f;
        g1 = (vrx && vry) ? grbx * grby * mk : 0.f;
        g2 = (vlx && vry) ? gltx * grby * mk : 0.f;
        g3 = (vrx && vly) ? grbx * glty * mk : 0.f;

        int xlt = min(max(qltx - 1, 0), HH - 1);
        int ylt = min(max(qlty - 1, 0), WW - 1);
        int xrb = min(max(qrbx - 1, 0), HH - 1);
        int yrb = min(max(qrby - 1, 0), WW - 1);
        q0 = xtb + (size_t)(xlt * WW + ylt) * 64 + co;
        q1 = xtb + (size_t)(xrb * WW + yrb) * 64 + co;
        q2 = xtb + (size_t)(xlt * WW + yrb) * 64 + co;
        q3 = xtb + (size_t)(xrb * WW + ylt) * 64 + co;
    };

    // prologue: gathers + g for tap 0
    s8v c0a, c0b, c1a, c1b, c2a, c2b, c3a, c3b;
    float gc0, gc1, gc2, gc3;
    {
        const unsigned short *q0, *q1, *q2, *q3;
        desc(0, gc0, gc1, gc2, gc3, q0, q1, q2, q3);
        c0a = *(const s8v*)(q0); c0b = *(const s8v*)(q0 + 32);
        c1a = *(const s8v*)(q1); c1b = *(const s8v*)(q1 + 32);
        c2a = *(const s8v*)(q2); c2b = *(const s8v*)(q2 + 32);
        c3a = *(const s8v*)(q3); c3b = *(const s8v*)(q3 + 32);
    }

#pragma unroll 3
    for (int kt = 0; kt < 9; kt++) {
        // A for tap kt — issued FIRST (FIFO: its wait drains only this tap's gathers)
        const unsigned short* a = wcb + ln15 * 576 + kt * 64 + co;
        s8v a0k0 = *(const s8v*)(a);
        s8v a0k1 = *(const s8v*)(a + 32);
        s8v a1k0 = *(const s8v*)(a + 16 * 576);
        s8v a1k1 = *(const s8v*)(a + 16 * 576 + 32);
        s8v a2k0 = *(const s8v*)(a + 32 * 576);
        s8v a2k1 = *(const s8v*)(a + 32 * 576 + 32);
        s8v a3k0 = *(const s8v*)(a + 48 * 576);
        s8v a3k1 = *(const s8v*)(a + 48 * 576 + 32);
        // gathers for tap kt+1 — stay in flight through this tap's MFMA
        s8v n0a = zs, n0b = zs, n1a = zs, n1b = zs, n2a = zs, n2b = zs, n3a = zs, n3b = zs;
        float ng0 = 0.f, ng1 = 0.f, ng2 = 0.f, ng3 = 0.f;
        if (kt < 8) {
            const unsigned short *q0, *q1, *q2, *q3;
            desc(kt + 1, ng0, ng1, ng2, ng3, q0, q1, q2, q3);
            n0a = *(const s8v*)(q0); n0b = *(const s8v*)(q0 + 32);
            n1a = *(const s8v*)(q1); n1b = *(const s8v*)(q1 + 32);
            n2a = *(const s8v*)(q2); n2b = *(const s8v*)(q2 + 32);
            n3a = *(const s8v*)(q3); n3b = *(const s8v*)(q3 + 32);
        }
        // per-corner GEMM + f32 fold
        {
            f4v d0 = MF(a0k0, c0a, zf), d1 = MF(a1k0, c0a, zf),
                d2 = MF(a2k0, c0a, zf), d3 = MF(a3k0, c0a, zf);
            d0 = MF(a0k1, c0b, d0); d1 = MF(a1k1, c0b, d1);
            d2 = MF(a2k1, c0b, d2); d3 = MF(a3k1, c0b, d3);
            FOLD(gc0, d0, o0); FOLD(gc0, d1, o1); FOLD(gc0, d2, o2); FOLD(gc0, d3, o3);
        }
        {
            f4v d0 = MF(a0k0, c1a, zf), d1 = MF(a1k0, c1a, zf),
                d2 = MF(a2k0, c1a, zf), d3 = MF(a3k0, c1a, zf);
            d0 = MF(a0k1, c1b, d0); d1 = MF(a1k1, c1b, d1);
            d2 = MF(a2k1, c1b, d2); d3 = MF(a3k1, c1b, d3);
            FOLD(gc1, d0, o0); FOLD(gc1, d1, o1); FOLD(gc1, d2, o2); FOLD(gc1, d3, o3);
        }
        {
            f4v d0 = MF(a0k0, c2a, zf), d1 = MF(a1k0, c2a, zf),
                d2 = MF(a2k0, c2a, zf), d3 = MF(a3k0, c2a, zf);
            d0 = MF(a0k1, c2b, d0); d1 = MF(a1k1, c2b, d1);
            d2 = MF(a2k1, c2b, d2); d3 = MF(a3k1, c2b, d3);
            FOLD(gc2, d0, o0); FOLD(gc2, d1, o1); FOLD(gc2, d2, o2); FOLD(gc2, d3, o3);
        }
        {
            f4v d0 = MF(a0k0, c3a, zf), d1 = MF(a1k0, c3a, zf),
                d2 = MF(a2k0, c3a, zf), d3 = MF(a3k0, c3a, zf);
            d0 = MF(a0k1, c3b, d0); d1 = MF(a1k1, c3b, d1);
            d2 = MF(a2k1, c3b, d2); d3 = MF(a3k1, c3b, d3);
            FOLD(gc3, d0, o0); FOLD(gc3, d1, o1); FOLD(gc3, d2, o2); FOLD(gc3, d3, o3);
        }
        // rotate pipeline
        c0a = n0a; c0b = n0b; c1a = n1a; c1b = n1b;
        c2a = n2a; c2b = n2b; c3a = n3a; c3b = n3b;
        gc0 = ng0; gc1 = ng1; gc2 = ng2; gc3 = ng3;
    }

    // epilogue: D col = pixel, row = oc
    int pix = hw0 + ln15;
    float* ob = out + (size_t)b * (OO * HW) + pix;
#pragma unroll
    for (int r = 0; r < 4; r++) {
        ob[(size_t)(0 * 16 + quad * 4 + r) * HW] = o0[r];
        ob[(size_t)(1 * 16 + quad * 4 + r) * HW] = o1[r];
        ob[(size_t)(2 * 16 + quad * 4 + r) * HW] = o2[r];
        ob[(size_t)(3 * 16 + quad * 4 + r) * HW] = o3[r];
    }
}

extern "C" void kernel_launch(void* const* d_in, const int* in_sizes, int n_in,
                              void* d_out, int out_size, void* d_ws, size_t ws_size,
                              hipStream_t stream) {
    const float* x   = (const float*)d_in[0];
    const float* wp  = (const float*)d_in[1];
    const float* bp  = (const float*)d_in[2];
    const float* wm  = (const float*)d_in[3];
    const float* bm  = (const float*)d_in[4];
    const float* wcv = (const float*)d_in[5];
    float* ws = (float*)d_ws;
    float* out = (float*)d_out;

    hipLaunchKernelGGL(k_pxt, dim3(1248), dim3(256), 0, stream, x, wp, bp, wm, bm, wcv, ws);
    hipLaunchKernelGGL(k_main, dim3(1024), dim3(256), 0, stream, ws, out);
}

// Round 6
// 142.515 us; speedup vs baseline: 1.1752x; 1.1752x over previous
//
#include <hip/hip_runtime.h>
#include <hip/hip_bf16.h>

// DCNv2: B=4, C=64, H=W=128, O=64, KS=3, N=9, PAD=1. I/O float32.
#define BB 4
#define CC 64
#define HH 128
#define WW 128
#define OO 64
#define NN 9
#define HW 16384
#define HP 130
#define WP 130

// ---- ws layout (float-slot offsets) ----
// 0        wpmb bf16 [32][576]   (rows 0..17 w_p, 18..26 w_m, 27..31 zero)
// 9216     bias fp32 (18 b_p then 9 b_m)
// 9248     wcb  bf16 [o(64)][K(576)], K = kt*64+c
// 27680    xt   bf16 [b][hw][c]
#define WPMB_F  0
#define BPM_OFF 9216
#define WCB_F   9248
#define XT_F    27680

typedef __attribute__((ext_vector_type(8))) short s8v;
typedef __attribute__((ext_vector_type(8))) unsigned short u8v;
typedef __attribute__((ext_vector_type(4))) float f4v;

__device__ __forceinline__ unsigned short f2bu(float f) {   // fp32 -> bf16 bits (RNE)
    unsigned int b = __float_as_uint(f);
    return (unsigned short)((b + 0x7FFFu + ((b >> 16) & 1u)) >> 16);
}
__device__ __forceinline__ float bu2f(unsigned short u) {
    return __uint_as_float(((unsigned int)u) << 16);
}

// blocks [0,1024): NCHW fp32 -> NHWC bf16 transpose via LDS tile (XCD-swizzled
// to match k_main's consumer mapping). blocks [1024,1248): weight prep.
__global__ void __launch_bounds__(256) k_pxt(const float* __restrict__ x,
                                             const float* __restrict__ wp,
                                             const float* __restrict__ bp,
                                             const float* __restrict__ wm,
                                             const float* __restrict__ bm,
                                             const float* __restrict__ wcv,
                                             float* __restrict__ ws) {
    int blk = blockIdx.x;
    int t = threadIdx.x;
    if (blk >= 1024) {                       // ---- weight prep path ----
        int tid = (blk - 1024) * 256 + t;
        if (tid < 18432) {                   // wpmb [32][576]
            int r = tid / 576;
            int kk = tid % 576;              // kk = kt*64 + c
            int kt = kk >> 6;
            int c = kk & 63;
            int dy = kt / 3, dx = kt % 3;
            float v = 0.f;
            if (r < 18)       v = wp[((r * 64 + c) * 3 + dy) * 3 + dx];
            else if (r < 27)  v = wm[(((r - 18) * 64 + c) * 3 + dy) * 3 + dx];
            ((unsigned short*)(ws + WPMB_F))[tid] = f2bu(v);
        } else if (tid < 18459) {
            int i = tid - 18432;
            ws[BPM_OFF + i] = (i < 18) ? bp[i] : bm[i - 18];
        } else if (tid >= 20480) {           // wcb [64][576], tid < 57344 by grid
            int d = tid - 20480;
            int o = d / 576;
            int kk = d % 576;
            int kt = kk >> 6;
            int c = kk & 63;
            ((unsigned short*)(ws + WCB_F))[o * 576 + kk] = f2bu(wcv[(o * 64 + c) * 9 + kt]);
        }
        return;
    }
    // ---- transpose: block = 64 hw x 64 ch, tile stored [hw][c] ----
    __shared__ unsigned short tile[64][72];   // 16B-aligned rows (144B)
    int sb = ((blk & 7) << 7) | (blk >> 3);   // XCD-chunked bijection on [0,1024)
    int b = sb >> 8;
    int hw0 = (sb & 255) * 64;
    unsigned short* xt = (unsigned short*)(ws + XT_F);

#pragma unroll
    for (int p = 0; p < 4; p++) {            // coalesced float4 reads: 256B/instr per c-row
        int c = p * 16 + (t >> 4);
        int h4 = (t & 15) * 4;
        float4 v = *(const float4*)(x + ((size_t)(b * 64 + c)) * HW + hw0 + h4);
        tile[h4 + 0][c] = f2bu(v.x);
        tile[h4 + 1][c] = f2bu(v.y);
        tile[h4 + 2][c] = f2bu(v.z);
        tile[h4 + 3][c] = f2bu(v.w);
    }
    __syncthreads();
#pragma unroll
    for (int p = 0; p < 2; p++) {            // contiguous 16B/lane stores: 1KB/wave
        int hw = p * 32 + (t >> 3);
        int cb = (t & 7) * 8;
        u8v o = *(const u8v*)(&tile[hw][cb]);
        *(u8v*)(xt + ((size_t)(b * HW + hw0 + hw)) * 64 + cb) = o;
    }
}

// Fused offset-conv + sampler + einsum, fully WAVE-SYNCHRONOUS (zero __syncthreads).
// Each wave owns 16 pixels end-to-end; all LDS regions are per-wave.
// A fragments come direct from global, issued FIRST each iteration so the MFMA's
// vmcnt wait drains only A and leaves the prefetch gathers in flight (FIFO order).
// XCD-chunked block swizzle keeps each XCD's gathers inside its own L2.
__global__ void __launch_bounds__(256) k_main(const float* __restrict__ ws,
                                              float* __restrict__ out) {
    __shared__ unsigned short Sld[4][2][16 * 72];   // [wave][buf][pix*72]
    __shared__ float pxmL[4][3][NN][16];            // [wave][{px,py,m}][tap][pix]

    int t = threadIdx.x;
    int lane = t & 63;
    int wv = t >> 6;
    int ln15 = lane & 15;
    int quad = lane >> 4;

    int braw = blockIdx.x;                   // 1024 = 8 XCD * 128: chunked swizzle
    int blk = ((braw & 7) << 7) | (braw >> 3);
    int b = blk >> 8;
    int hw0 = (blk & 255) * 64 + wv * 16;    // this wave's 16-pixel base

    const unsigned short* wpmb = (const unsigned short*)(ws + WPMB_F);
    const unsigned short* wcb = (const unsigned short*)(ws + WCB_F);
    const unsigned short* xtb = (const unsigned short*)(ws + XT_F) + (size_t)b * HW * 64;
    const float* bpm = ws + BPM_OFF;

    // sampler/stager lane roles: 16 pixels x 4 channel-groups
    int ip = lane >> 2;              // wave-local pixel 0..15
    int cg = lane & 3;
    int cbase = cg * 16;
    int ph = (hw0 + ip) >> 7;
    int pw = (hw0 + ip) & 127;

    unsigned short* S0 = &Sld[wv][0][0];
    unsigned short* S1 = &Sld[wv][1][0];
    const u8v z = (u8v){0, 0, 0, 0, 0, 0, 0, 0};

    // ================= PHASE 1: offset/modulation GEMM (M=27, K=576) =================
    {
        f4v acc1[2];
        acc1[0] = (f4v){0.f, 0.f, 0.f, 0.f};
        acc1[1] = (f4v){0.f, 0.f, 0.f, 0.f};

        // prologue: stage B(kt=0), dy=0 dx=0
        {
            int h2 = ph - 1, w2 = pw - 1;
            bool val = ((unsigned)h2 < 128u) && ((unsigned)w2 < 128u);
            u8v e0 = z, e1 = z;
            if (val) {
                const unsigned short* src = xtb + ((size_t)(h2 * 128 + w2)) * 64 + cbase;
                e0 = *(const u8v*)(src);
                e1 = *(const u8v*)(src + 8);
            }
            *(u8v*)(&S0[ip * 72 + cbase]) = e0;
            *(u8v*)(&S0[ip * 72 + cbase + 8]) = e1;
        }
        __builtin_amdgcn_wave_barrier();

#pragma unroll 1
        for (int kt = 0; kt < 9; kt++) {
            unsigned short* cur = (kt & 1) ? S1 : S0;
            unsigned short* nxt = (kt & 1) ? S0 : S1;
            // A fragments for kt — issue FIRST (vmcnt FIFO discipline)
            s8v a00 = *(const s8v*)(wpmb + ln15 * 576 + kt * 64 + quad * 8);
            s8v a01 = *(const s8v*)(wpmb + ln15 * 576 + kt * 64 + 32 + quad * 8);
            s8v a10 = *(const s8v*)(wpmb + (16 + ln15) * 576 + kt * 64 + quad * 8);
            s8v a11 = *(const s8v*)(wpmb + (16 + ln15) * 576 + kt * 64 + 32 + quad * 8);
            // B tile for kt+1 — issued after A, stays in flight through MFMA
            u8v n0 = z, n1 = z;
            if (kt < 8) {
                int k2 = kt + 1;
                int dy = k2 / 3, dx = k2 % 3;
                int h2 = ph + dy - 1, w2 = pw + dx - 1;
                bool val = ((unsigned)h2 < 128u) && ((unsigned)w2 < 128u);
                if (val) {
                    const unsigned short* src = xtb + ((size_t)(h2 * 128 + w2)) * 64 + cbase;
                    n0 = *(const u8v*)(src);
                    n1 = *(const u8v*)(src + 8);
                }
            }
            // MFMA on current buffer (B from LDS, A waits drain only A)
            {
                s8v bf0 = *(const s8v*)(&cur[ln15 * 72 + quad * 8]);
                s8v bf1 = *(const s8v*)(&cur[ln15 * 72 + 32 + quad * 8]);
                acc1[0] = __builtin_amdgcn_mfma_f32_16x16x32_bf16(a00, bf0, acc1[0], 0, 0, 0);
                acc1[1] = __builtin_amdgcn_mfma_f32_16x16x32_bf16(a10, bf0, acc1[1], 0, 0, 0);
                acc1[0] = __builtin_amdgcn_mfma_f32_16x16x32_bf16(a01, bf1, acc1[0], 0, 0, 0);
                acc1[1] = __builtin_amdgcn_mfma_f32_16x16x32_bf16(a11, bf1, acc1[1], 0, 0, 0);
            }
            if (kt < 8) {
                *(u8v*)(&nxt[ip * 72 + cbase]) = n0;
                *(u8v*)(&nxt[ip * 72 + cbase + 8]) = n1;
            }
            __builtin_amdgcn_wave_barrier();
        }

        // epilogue -> per-wave LDS pxm. pixel = ln15, oc = mt*16 + quad*4 + r
        int gp = hw0 + ln15;
        int h = gp >> 7, w = gp & 127;
#pragma unroll
        for (int mt = 0; mt < 2; mt++) {
#pragma unroll
            for (int r = 0; r < 4; r++) {
                int oc = mt * 16 + quad * 4 + r;
                if (oc < 27) {
                    float v = acc1[mt][r] + bpm[oc];
                    if (oc < 9) {
                        int ki = oc / 3;
                        pxmL[wv][0][oc][ln15] = v + (float)(ki - 1) + (float)(h + 1);
                    } else if (oc < 18) {
                        int k = oc - 9;
                        int kj = k % 3;
                        pxmL[wv][1][k][ln15] = v + (float)(kj - 1) + (float)(w + 1);
                    } else {
                        int k = oc - 18;
                        pxmL[wv][2][k][ln15] = 1.f / (1.f + __expf(-v));
                    }
                }
            }
        }
    }
    __builtin_amdgcn_wave_barrier();

    // ================= PHASE 2: sample + einsum GEMM (M=64, K=576) =================
    f4v acc[4];
#pragma unroll
    for (int mt = 0; mt < 4; mt++) acc[mt] = (f4v){0.f, 0.f, 0.f, 0.f};

    auto desc = [&](int kt,
                    float& g0, float& g1, float& g2, float& g3,
                    int& o0, int& o1, int& o2, int& o3) {
        float px = pxmL[wv][0][kt][ip];
        float py = pxmL[wv][1][kt][ip];
        float mk = pxmL[wv][2][kt][ip];
        float fx = floorf(px), fy = floorf(py);
        float pxc = fminf(fmaxf(px, 0.f), (float)(HP - 1));
        float pyc = fminf(fmaxf(py, 0.f), (float)(WP - 1));
        int qltx = (int)fminf(fmaxf(fx, 0.f), (float)(HP - 1));
        int qlty = (int)fminf(fmaxf(fy, 0.f), (float)(WP - 1));
        int qrbx = (int)fminf(fmaxf(fx + 1.f, 0.f), (float)(HP - 1));
        int qrby = (int)fminf(fmaxf(fy + 1.f, 0.f), (float)(WP - 1));

        float gltx = 1.f + ((float)qltx - pxc);
        float glty = 1.f + ((float)qlty - pyc);
        float grbx = 1.f - ((float)qrbx - pxc);
        float grby = 1.f - ((float)qrby - pyc);

        bool vlx = (qltx >= 1) && (qltx <= HH);
        bool vly = (qlty >= 1) && (qlty <= WW);
        bool vrx = (qrbx >= 1) && (qrbx <= HH);
        bool vry = (qrby >= 1) && (qrby <= WW);
        g0 = (vlx && vly) ? gltx * glty * mk : 0.f;
        g1 = (vrx && vry) ? grbx * grby * mk : 0.f;
        g2 = (vlx && vry) ? gltx * grby * mk : 0.f;
        g3 = (vrx && vly) ? grbx * glty * mk : 0.f;

        int xlt = min(max(qltx - 1, 0), HH - 1);
        int ylt = min(max(qlty - 1, 0), WW - 1);
        int xrb = min(max(qrbx - 1, 0), HH - 1);
        int yrb = min(max(qrby - 1, 0), WW - 1);
        o0 = (xlt * WW + ylt) * 64 + cbase;
        o1 = (xrb * WW + yrb) * 64 + cbase;
        o2 = (xlt * WW + yrb) * 64 + cbase;
        o3 = (xrb * WW + ylt) * 64 + cbase;
    };

    // prologue: sample kt=0 into buffer 0
    {
        float g0, g1, g2, g3; int o0, o1, o2, o3;
        desc(0, g0, g1, g2, g3, o0, o1, o2, o3);
        u8v e0a = *(const u8v*)(xtb + o0), e0b = *(const u8v*)(xtb + o0 + 8);
        u8v e1a = *(const u8v*)(xtb + o1), e1b = *(const u8v*)(xtb + o1 + 8);
        u8v e2a = *(const u8v*)(xtb + o2), e2b = *(const u8v*)(xtb + o2 + 8);
        u8v e3a = *(const u8v*)(xtb + o3), e3b = *(const u8v*)(xtb + o3 + 8);
        u8v sva, svb;
#pragma unroll
        for (int j = 0; j < 8; j++) {
            float va = g0 * bu2f(e0a[j]) + g1 * bu2f(e1a[j])
                     + g2 * bu2f(e2a[j]) + g3 * bu2f(e3a[j]);
            float vb = g0 * bu2f(e0b[j]) + g1 * bu2f(e1b[j])
                     + g2 * bu2f(e2b[j]) + g3 * bu2f(e3b[j]);
            sva[j] = f2bu(va);
            svb[j] = f2bu(vb);
        }
        *(u8v*)(&S0[ip * 72 + cbase]) = sva;
        *(u8v*)(&S0[ip * 72 + cbase + 8]) = svb;
    }
    __builtin_amdgcn_wave_barrier();

#pragma unroll 1
    for (int kt = 0; kt < 9; kt++) {
        unsigned short* cur = (kt & 1) ? S1 : S0;
        unsigned short* nxt = (kt & 1) ? S0 : S1;
        // A fragments for kt — issue FIRST so MFMA's vmcnt drains only these
        s8v A[4][2];
#pragma unroll
        for (int mt = 0; mt < 4; mt++) {
#pragma unroll
            for (int ks = 0; ks < 2; ks++) {
                A[mt][ks] = *(const s8v*)(wcb + (mt * 16 + ln15) * 576 + kt * 64 + ks * 32 + quad * 8);
            }
        }
        // gathers for kt+1 — stay in flight through the MFMA phase
        float g0 = 0.f, g1 = 0.f, g2 = 0.f, g3 = 0.f;
        u8v e0a, e0b, e1a, e1b, e2a, e2b, e3a, e3b;
        if (kt < 8) {
            int o0, o1, o2, o3;
            desc(kt + 1, g0, g1, g2, g3, o0, o1, o2, o3);
            e0a = *(const u8v*)(xtb + o0); e0b = *(const u8v*)(xtb + o0 + 8);
            e1a = *(const u8v*)(xtb + o1); e1b = *(const u8v*)(xtb + o1 + 8);
            e2a = *(const u8v*)(xtb + o2); e2b = *(const u8v*)(xtb + o2 + 8);
            e3a = *(const u8v*)(xtb + o3); e3b = *(const u8v*)(xtb + o3 + 8);
        }
        // MFMA on current buffer
#pragma unroll
        for (int ks = 0; ks < 2; ks++) {
            s8v bf = *(const s8v*)(&cur[ln15 * 72 + ks * 32 + quad * 8]);
#pragma unroll
            for (int mt = 0; mt < 4; mt++) {
                acc[mt] = __builtin_amdgcn_mfma_f32_16x16x32_bf16(A[mt][ks], bf, acc[mt], 0, 0, 0);
            }
        }
        // blend after MFMA, write other buffer
        if (kt < 8) {
            u8v sva, svb;
#pragma unroll
            for (int j = 0; j < 8; j++) {
                float va = g0 * bu2f(e0a[j]) + g1 * bu2f(e1a[j])
                         + g2 * bu2f(e2a[j]) + g3 * bu2f(e3a[j]);
                float vb = g0 * bu2f(e0b[j]) + g1 * bu2f(e1b[j])
                         + g2 * bu2f(e2b[j]) + g3 * bu2f(e3b[j]);
                sva[j] = f2bu(va);
                svb[j] = f2bu(vb);
            }
            *(u8v*)(&nxt[ip * 72 + cbase]) = sva;
            *(u8v*)(&nxt[ip * 72 + cbase + 8]) = svb;
        }
        __builtin_amdgcn_wave_barrier();
    }

    // epilogue: D col = pixel, row = oc
    int pix = hw0 + ln15;
    float* ob = out + (size_t)b * (OO * HW) + pix;
#pragma unroll
    for (int mt = 0; mt < 4; mt++) {
#pragma unroll
        for (int r = 0; r < 4; r++) {
            ob[(size_t)(mt * 16 + quad * 4 + r) * HW] = acc[mt][r];
        }
    }
}

extern "C" void kernel_launch(void* const* d_in, const int* in_sizes, int n_in,
                              void* d_out, int out_size, void* d_ws, size_t ws_size,
                              hipStream_t stream) {
    const float* x   = (const float*)d_in[0];
    const float* wp  = (const float*)d_in[1];
    const float* bp  = (const float*)d_in[2];
    const float* wm  = (const float*)d_in[3];
    const float* bm  = (const float*)d_in[4];
    const float* wcv = (const float*)d_in[5];
    float* ws = (float*)d_ws;
    float* out = (float*)d_out;

    hipLaunchKernelGGL(k_pxt, dim3(1248), dim3(256), 0, stream, x, wp, bp, wm, bm, wcv, ws);
    hipLaunchKernelGGL(k_main, dim3(1024), dim3(256), 0, stream, ws, out);
}